// Round 1
// baseline (5982.329 us; speedup 1.0000x reference)
//
#include <hip/hip_runtime.h>

// Bidirectional LSTM: V=32000, H=1024, S=512. fp32 in/out.
// SINGLE fused persistent kernel.
//   - 256 blocks x 512 threads launched; only blocks with (b&7)<4 are active
//     (128 blocks). Assuming round-robin block->XCD dispatch, dir 0 lives on
//     XCDs {0,1}, dir 1 on {2,3}: h-line invalidate/refetch fan-out 8->2.
//   - Per active block: 16 units (64 gate-rows). Wh row-slices in registers
//     (w[128] fp32/thread). Wx row-slices bf16-packed in 128KB dynamic LDS.
//   - gx (= Wx.x + bias) is computed IN the poll slack each step (x_t known
//     a step ahead; x prefetched to LDS double buffer). No separate GEMM.
//   - h exchange: self-announcing 8B words {tag=t+1 | fp32 h}, relaxed
//     agent-scope atomics, double-buffered by step parity (unchanged scheme).
//     Each block's 16 h words = one 128B line (clean line ownership).

#define HID 1024
#define SEQ 512

__device__ __forceinline__ unsigned int f2bf(float f) {
  union { float f; unsigned int i; } v; v.f = f;
  unsigned int u = v.i;
  return (u + 0x7fffu + ((u >> 16) & 1u)) >> 16;  // RNE
}
__device__ __forceinline__ unsigned int pk(float lo, float hi) {
  return f2bf(lo) | (f2bf(hi) << 16);
}
__device__ __forceinline__ float bflo(unsigned int u) {
  union { unsigned int i; float f; } v; v.i = u << 16; return v.f;
}
__device__ __forceinline__ float bfhi(unsigned int u) {
  union { unsigned int i; float f; } v; v.i = u & 0xffff0000u; return v.f;
}
__device__ __forceinline__ float sigm(float x) { return 1.f / (1.f + __expf(-x)); }
__device__ __forceinline__ float ftanh(float x) {
  // tanh(x) = 1 - 2/(exp(2x)+1); saturates correctly at +-inf. ~1e-6 abs err.
  return 1.f - 2.f / (__expf(2.f * x) + 1.f);
}

__global__ __launch_bounds__(512, 2)
void bilstm_kernel(const int* __restrict__ tokens,
                   const float* __restrict__ emb,
                   const float* __restrict__ Wxf, const float* __restrict__ Whf,
                   const float* __restrict__ bxf, const float* __restrict__ bhf,
                   const float* __restrict__ Wxb, const float* __restrict__ Whb,
                   const float* __restrict__ bxb, const float* __restrict__ bhb,
                   unsigned long long* h_ex,     // [2][2][1024] u64
                   float* __restrict__ out)      // [SEQ][2048] fp32
{
  extern __shared__ unsigned char smem[];        // 128KB: wx bf16-packed
  uint4* wx_lds = (uint4*)smem;                  // [m][tid] : wx_lds[m*512+tid]
  __shared__ alignas(16) float hs[HID];
  __shared__ alignas(16) float xbuf[2][HID];
  __shared__ float g_red[64];

  const int b = blockIdx.x;
  const int xcd = b & 7;
  if (xcd >= 4) return;                          // 128 active blocks
  const int d  = xcd >> 1;                       // dir: XCD{0,1}->0, {2,3}->1
  const int db = (b >> 3) * 2 + (xcd & 1);       // 0..63 within direction
  const int tid = threadIdx.x;
  const int r   = tid >> 3;                      // 0..63: row = unit_l*4+gate
  const int kc  = tid & 7;                       // 8-way k split
  const int unit = db * 16 + (r >> 2);
  const int gate = r & 3;
  const float* Wh  = d ? Whb : Whf;
  const float* Wxp = d ? Wxb : Wxf;

  // --- init: Wh slice -> registers, Wx slice -> LDS (bf16 pairs) ---
  float w[128];
  {
    const float* wrow = Wh  + ((size_t)gate * HID + unit) * HID + kc * 8;
    const float* xrow = Wxp + ((size_t)gate * HID + unit) * HID + kc * 8;
    #pragma unroll
    for (int m = 0; m < 16; ++m) {
      const float4 q0 = *(const float4*)(wrow + m * 64);
      const float4 q1 = *(const float4*)(wrow + m * 64 + 4);
      w[m*8+0] = q0.x; w[m*8+1] = q0.y; w[m*8+2] = q0.z; w[m*8+3] = q0.w;
      w[m*8+4] = q1.x; w[m*8+5] = q1.y; w[m*8+6] = q1.z; w[m*8+7] = q1.w;
      const float4 p0 = *(const float4*)(xrow + m * 64);
      const float4 p1 = *(const float4*)(xrow + m * 64 + 4);
      uint4 pq;
      pq.x = pk(p0.x, p0.y); pq.y = pk(p0.z, p0.w);
      pq.z = pk(p1.x, p1.y); pq.w = pk(p1.z, p1.w);
      wx_lds[m * 512 + tid] = pq;                // [m][tid]: lane-consecutive
    }
  }

  float bias = 0.f;
  if (tid < 64) {
    const int row = (tid & 3) * HID + db * 16 + (tid >> 2);
    bias = (d ? bxb[row] : bxf[row]) + (d ? bhb[row] : bhf[row]);
  }

  // x(0) -> xbuf[0]
  {
    const int s0 = d ? (SEQ - 1) : 0;
    const float2 v = *(const float2*)(emb + (size_t)tokens[s0] * HID + tid * 2);
    *(float2*)(&xbuf[0][tid * 2]) = v;
  }
  __syncthreads();                               // covers wx_lds + xbuf[0]

  float c_state = 0.f;                           // lives on tid<64 && cg==0

  for (int t = 0; t < SEQ; ++t) {
    const int par  = t & 1;
    const int s_io = d ? (SEQ - 1 - t) : t;
    const bool pf  = (t + 1 < SEQ);

    // (1) issue x(t+1) prefetch (lands in regs; written to LDS after poll)
    float2 xf = {0.f, 0.f};
    if (pf) {
      const int sn = d ? (SEQ - 2 - t) : (t + 1);
      xf = *(const float2*)(emb + (size_t)tokens[sn] * HID + tid * 2);
    }

    // (2) acc_x: this row's Wx.x partial over the thread's 128 k's.
    //     Depends only on x_t -> runs in the poll slack, off critical path.
    float axv[4] = {0.f, 0.f, 0.f, 0.f};
    {
      const float* xb = xbuf[par];
      #pragma unroll
      for (int m = 0; m < 16; ++m) {
        const uint4  wq = wx_lds[m * 512 + tid];
        const float4 a  = *(const float4*)(&xb[kc * 8 + m * 64]);
        const float4 c4 = *(const float4*)(&xb[kc * 8 + m * 64 + 4]);
        axv[m & 3] += bflo(wq.x) * a.x  + bfhi(wq.x) * a.y
                    + bflo(wq.y) * a.z  + bfhi(wq.y) * a.w
                    + bflo(wq.z) * c4.x + bfhi(wq.z) * c4.y
                    + bflo(wq.w) * c4.z + bfhi(wq.w) * c4.w;
      }
    }

    // (3) stage a: h_{t-1} -> hs (self-announcing poll, 2 words/thread)
    const int base = tid * 2;
    if (t == 0) {
      hs[base] = 0.f; hs[base + 1] = 0.f;
    } else {
      const unsigned long long* hp = h_ex + ((size_t)d * 2 + ((t - 1) & 1)) * HID;
      const unsigned int need = (unsigned int)t;
      unsigned long long u0, u1;
      for (;;) {
        u0 = __hip_atomic_load(hp + base + 0, __ATOMIC_RELAXED, __HIP_MEMORY_SCOPE_AGENT);
        u1 = __hip_atomic_load(hp + base + 1, __ATOMIC_RELAXED, __HIP_MEMORY_SCOPE_AGENT);
        if (((unsigned int)(u0 >> 32) == need) & ((unsigned int)(u1 >> 32) == need))
          break;
        __builtin_amdgcn_s_sleep(1);
      }
      hs[base + 0] = __uint_as_float((unsigned int)u0);
      hs[base + 1] = __uint_as_float((unsigned int)u1);
    }

    // (4) x(t+1) -> LDS (slot par^1: its last readers finished at t-1)
    if (pf) *(float2*)(&xbuf[par ^ 1][tid * 2]) = xf;
    __syncthreads();

    // (6) stage b: Wh.h partial (4 accumulators: dep chain 128 -> 32)
    float ah[4] = {0.f, 0.f, 0.f, 0.f};
    #pragma unroll
    for (int m = 0; m < 16; ++m) {
      const float4 a  = *(const float4*)(&hs[kc * 8 + m * 64]);
      const float4 c4 = *(const float4*)(&hs[kc * 8 + m * 64 + 4]);
      ah[m & 3] += w[m*8+0] * a.x  + w[m*8+1] * a.y
                 + w[m*8+2] * a.z  + w[m*8+3] * a.w
                 + w[m*8+4] * c4.x + w[m*8+5] * c4.y
                 + w[m*8+6] * c4.z + w[m*8+7] * c4.w;
    }
    float acc = ((ah[0] + ah[1]) + (ah[2] + ah[3]))
              + ((axv[0] + axv[1]) + (axv[2] + axv[3]));
    acc += __shfl_xor(acc, 1);
    acc += __shfl_xor(acc, 2);
    acc += __shfl_xor(acc, 4);
    if (kc == 0) g_red[r] = acc;
    __syncthreads();

    // (8) stage c: gates on 64 lanes, combine on 16 unit-lanes, publish
    if (tid < 64) {
      const float gsum = g_red[tid] + bias;
      const int cu = tid >> 2, cg = tid & 3;
      const float a = (cg == 3) ? ftanh(gsum) : sigm(gsum);
      const float ai  = __shfl(a, cu * 4 + 0);
      const float af_ = __shfl(a, cu * 4 + 1);
      const float ao  = __shfl(a, cu * 4 + 2);
      const float ag  = __shfl(a, cu * 4 + 3);
      if (cg == 0) {
        c_state = af_ * c_state + ai * ag;
        const float hv = ao * ftanh(c_state);
        const int ug = db * 16 + cu;
        const unsigned long long pkd =
            ((unsigned long long)(unsigned int)(t + 1) << 32)
          | (unsigned long long)__float_as_uint(hv);
        __hip_atomic_store(h_ex + ((size_t)d * 2 + par) * HID + ug, pkd,
                           __ATOMIC_RELAXED, __HIP_MEMORY_SCOPE_AGENT);
        out[(size_t)s_io * 2048 + d * HID + ug] = hv;
      }
    }
    // no end barrier: next hs/xbuf writes are fenced by this step's barriers
    // (same reasoning as previous version).
  }
}

// ---------------------------------------------------------------------------
extern "C" void kernel_launch(void* const* d_in, const int* in_sizes, int n_in,
                              void* d_out, int out_size, void* d_ws, size_t ws_size,
                              hipStream_t stream) {
  const int*   tokens = (const int*)d_in[0];
  const float* emb = (const float*)d_in[3];
  const float* Wxf = (const float*)d_in[4];
  const float* Whf = (const float*)d_in[5];
  const float* bxf = (const float*)d_in[6];
  const float* bhf = (const float*)d_in[7];
  const float* Wxb = (const float*)d_in[8];
  const float* Whb = (const float*)d_in[9];
  const float* bxb = (const float*)d_in[10];
  const float* bhb = (const float*)d_in[11];

  unsigned long long* h_ex = (unsigned long long*)d_ws;  // 32 KB

  // 128KB dynamic LDS (Wx slice). Static ~12.3KB on top; total <160KB/CU.
  hipFuncSetAttribute((const void*)bilstm_kernel,
                      hipFuncAttributeMaxDynamicSharedMemorySize, 131072);

  bilstm_kernel<<<dim3(256), dim3(512), 131072, stream>>>(
      tokens, emb, Wxf, Whf, bxf, bhf, Wxb, Whb, bxb, bhb,
      h_ex, (float*)d_out);
}

// Round 2
// 1735.204 us; speedup vs baseline: 3.4476x; 3.4476x over previous
//
#include <hip/hip_runtime.h>

// Bidirectional LSTM: V=32000, H=1024, S=512. fp32 in/out.
// SINGLE fused persistent kernel, 256 blocks x 256 threads (1 block/CU).
//
// Round-2 fix: round-1 spilled w[128] to scratch (512thr + launch_bounds(512,2)
// capped VGPRs at 128) -> 5.8 GB HBM refetch. Restore the PROVEN geometry:
// 256 threads, __launch_bounds__(256,1) -> 512-reg budget, w[128] stays in
// the unified VGPR/AGPR file (round-0 scan: VGPR=84, no HBM thrash).
//
//   - block b: dir d=(b&7)>>2 (XCD-concentrated: dir0 on XCD 0-3, dir1 on
//     4-7 if round-robin mapping holds; correctness never depends on it),
//     db=(b>>3)*4+(b&3) in 0..127. 8 units (32 gate-rows) per block.
//   - Wh row-slices in registers (w[128] fp32/thread).
//     Wx row-slices bf16-packed in 64KB dynamic LDS.
//   - gx (= Wx.x + bias) computed in the poll slack each step; x_t prefetched
//     a step ahead into an LDS double buffer. No separate GEMM kernel.
//   - h exchange: self-announcing 8B words {tag=t+1 | fp32 h}, relaxed
//     agent-scope atomics, double-buffered by step parity (proven scheme).

#define HID 1024
#define SEQ 512

__device__ __forceinline__ unsigned int f2bf(float f) {
  union { float f; unsigned int i; } v; v.f = f;
  unsigned int u = v.i;
  return (u + 0x7fffu + ((u >> 16) & 1u)) >> 16;  // RNE
}
__device__ __forceinline__ unsigned int pk(float lo, float hi) {
  return f2bf(lo) | (f2bf(hi) << 16);
}
__device__ __forceinline__ float bflo(unsigned int u) {
  union { unsigned int i; float f; } v; v.i = u << 16; return v.f;
}
__device__ __forceinline__ float bfhi(unsigned int u) {
  union { unsigned int i; float f; } v; v.i = u & 0xffff0000u; return v.f;
}
__device__ __forceinline__ float sigm(float x) { return 1.f / (1.f + __expf(-x)); }
__device__ __forceinline__ float ftanh(float x) {
  return 1.f - 2.f / (__expf(2.f * x) + 1.f);   // exact at saturation
}

__global__ __launch_bounds__(256, 1)
void bilstm_kernel(const int* __restrict__ tokens,
                   const float* __restrict__ emb,
                   const float* __restrict__ Wxf, const float* __restrict__ Whf,
                   const float* __restrict__ bxf, const float* __restrict__ bhf,
                   const float* __restrict__ Wxb, const float* __restrict__ Whb,
                   const float* __restrict__ bxb, const float* __restrict__ bhb,
                   unsigned long long* h_ex,     // [2][2][1024] u64
                   float* __restrict__ out)      // [SEQ][2048] fp32
{
  extern __shared__ unsigned char smem[];        // 64KB: wx bf16-packed
  uint4* wx_lds = (uint4*)smem;                  // wx_lds[m*256 + tid]
  __shared__ alignas(16) float hs[HID];
  __shared__ alignas(16) float xbuf[2][HID];
  __shared__ float g_red[32];

  const int b   = blockIdx.x;
  const int d   = (b & 7) >> 2;                  // dir by XCD half
  const int db  = (b >> 3) * 4 + (b & 3);        // 0..127 within direction
  const int tid = threadIdx.x;
  const int r   = tid >> 3;                      // 0..31: row = unit_l*4+gate
  const int kc  = tid & 7;                       // 8-way k split
  const int unit = db * 8 + (r >> 2);
  const int gate = r & 3;
  const float* Wh  = d ? Whb : Whf;
  const float* Wxp = d ? Wxb : Wxf;

  // --- init: Wh slice -> registers (fits: 256thr/1blk -> 512-reg budget),
  //           Wx slice -> LDS (bf16 pairs) ---
  float w[128];
  {
    const float* wrow = Wh  + ((size_t)gate * HID + unit) * HID + kc * 8;
    const float* xrow = Wxp + ((size_t)gate * HID + unit) * HID + kc * 8;
    #pragma unroll
    for (int m = 0; m < 16; ++m) {
      const float4 q0 = *(const float4*)(wrow + m * 64);
      const float4 q1 = *(const float4*)(wrow + m * 64 + 4);
      w[m*8+0] = q0.x; w[m*8+1] = q0.y; w[m*8+2] = q0.z; w[m*8+3] = q0.w;
      w[m*8+4] = q1.x; w[m*8+5] = q1.y; w[m*8+6] = q1.z; w[m*8+7] = q1.w;
      const float4 p0 = *(const float4*)(xrow + m * 64);
      const float4 p1 = *(const float4*)(xrow + m * 64 + 4);
      uint4 pq;
      pq.x = pk(p0.x, p0.y); pq.y = pk(p0.z, p0.w);
      pq.z = pk(p1.x, p1.y); pq.w = pk(p1.z, p1.w);
      wx_lds[m * 256 + tid] = pq;
    }
  }

  float bias = 0.f;
  if (tid < 32) {
    const int row = (tid & 3) * HID + db * 8 + (tid >> 2);   // gate*H + unit
    bias = (d ? bxb[row] : bxf[row]) + (d ? bhb[row] : bhf[row]);
  }

  // x(0) -> xbuf[0]
  {
    const int s0 = d ? (SEQ - 1) : 0;
    *(float4*)(&xbuf[0][tid * 4]) =
        *(const float4*)(emb + (size_t)tokens[s0] * HID + tid * 4);
  }
  __syncthreads();                               // covers wx_lds + xbuf[0]

  float c_state = 0.f;                           // lives on tid<32 && cg==0

  for (int t = 0; t < SEQ; ++t) {
    const int par  = t & 1;
    const int s_io = d ? (SEQ - 1 - t) : t;
    const bool pf  = (t + 1 < SEQ);

    // (1) issue x(t+1) prefetch (lands in regs; LDS write after the poll)
    float4 xf = {0.f, 0.f, 0.f, 0.f};
    if (pf) {
      const int sn = d ? (SEQ - 2 - t) : (t + 1);
      xf = *(const float4*)(emb + (size_t)tokens[sn] * HID + tid * 4);
    }

    // (2) acc_x: Wx.x partial over this thread's 128 k's. Depends only on
    //     x_t (already in LDS) -> runs in the poll slack, off critical path.
    float axv[4] = {0.f, 0.f, 0.f, 0.f};
    {
      const float* xb = xbuf[par];
      #pragma unroll
      for (int m = 0; m < 16; ++m) {
        const uint4  wq = wx_lds[m * 256 + tid];
        const float4 a  = *(const float4*)(&xb[kc * 8 + m * 64]);
        const float4 c4 = *(const float4*)(&xb[kc * 8 + m * 64 + 4]);
        axv[m & 3] += bflo(wq.x) * a.x  + bfhi(wq.x) * a.y
                    + bflo(wq.y) * a.z  + bfhi(wq.y) * a.w
                    + bflo(wq.z) * c4.x + bfhi(wq.z) * c4.y
                    + bflo(wq.w) * c4.z + bfhi(wq.w) * c4.w;
      }
    }

    // (3) stage a: h_{t-1} -> hs (self-announcing poll, 4 words/thread)
    const int base = tid * 4;
    if (t == 0) {
      #pragma unroll
      for (int i = 0; i < 4; ++i) hs[base + i] = 0.f;       // h0 == 0
    } else {
      const unsigned long long* hp = h_ex + ((size_t)d * 2 + ((t - 1) & 1)) * HID;
      const unsigned int need = (unsigned int)t;
      unsigned long long u0, u1, u2, u3;
      for (;;) {
        u0 = __hip_atomic_load(hp+base+0, __ATOMIC_RELAXED, __HIP_MEMORY_SCOPE_AGENT);
        u1 = __hip_atomic_load(hp+base+1, __ATOMIC_RELAXED, __HIP_MEMORY_SCOPE_AGENT);
        u2 = __hip_atomic_load(hp+base+2, __ATOMIC_RELAXED, __HIP_MEMORY_SCOPE_AGENT);
        u3 = __hip_atomic_load(hp+base+3, __ATOMIC_RELAXED, __HIP_MEMORY_SCOPE_AGENT);
        if (((unsigned int)(u0 >> 32) == need) & ((unsigned int)(u1 >> 32) == need) &
            ((unsigned int)(u2 >> 32) == need) & ((unsigned int)(u3 >> 32) == need))
          break;
        __builtin_amdgcn_s_sleep(1);
      }
      hs[base+0] = __uint_as_float((unsigned int)u0);
      hs[base+1] = __uint_as_float((unsigned int)u1);
      hs[base+2] = __uint_as_float((unsigned int)u2);
      hs[base+3] = __uint_as_float((unsigned int)u3);
    }

    // (4) x(t+1) -> LDS slot par^1 (its last readers finished at step t-1's
    //     stage-b barrier; see race analysis in session notes)
    if (pf) *(float4*)(&xbuf[par ^ 1][tid * 4]) = xf;
    __syncthreads();

    // (5) stage b: Wh.h partial (4 accumulators: dep chain 128 -> 32)
    float ah[4] = {0.f, 0.f, 0.f, 0.f};
    #pragma unroll
    for (int m = 0; m < 16; ++m) {
      const float4 a  = *(const float4*)(&hs[kc * 8 + m * 64]);
      const float4 c4 = *(const float4*)(&hs[kc * 8 + m * 64 + 4]);
      ah[m & 3] += w[m*8+0] * a.x  + w[m*8+1] * a.y
                 + w[m*8+2] * a.z  + w[m*8+3] * a.w
                 + w[m*8+4] * c4.x + w[m*8+5] * c4.y
                 + w[m*8+6] * c4.z + w[m*8+7] * c4.w;
    }
    float acc = ((ah[0] + ah[1]) + (ah[2] + ah[3]))
              + ((axv[0] + axv[1]) + (axv[2] + axv[3]));
    acc += __shfl_xor(acc, 1);
    acc += __shfl_xor(acc, 2);
    acc += __shfl_xor(acc, 4);
    if (kc == 0) g_red[r] = acc;
    __syncthreads();

    // (6) stage c: gates on 32 lanes, combine on 8 unit-lanes, publish
    if (tid < 32) {
      const float gsum = g_red[tid] + bias;
      const int cu = tid >> 2, cg = tid & 3;
      const float a = (cg == 3) ? ftanh(gsum) : sigm(gsum);
      const float ai  = __shfl(a, cu * 4 + 0);
      const float af_ = __shfl(a, cu * 4 + 1);
      const float ao  = __shfl(a, cu * 4 + 2);
      const float ag  = __shfl(a, cu * 4 + 3);
      if (cg == 0) {
        c_state = af_ * c_state + ai * ag;
        const float hv = ao * ftanh(c_state);
        const int ug = db * 8 + cu;
        const unsigned long long pkd =
            ((unsigned long long)(unsigned int)(t + 1) << 32)
          | (unsigned long long)__float_as_uint(hv);
        __hip_atomic_store(h_ex + ((size_t)d * 2 + par) * HID + ug, pkd,
                           __ATOMIC_RELAXED, __HIP_MEMORY_SCOPE_AGENT);
        out[(size_t)s_io * 2048 + d * HID + ug] = hv;
      }
    }
    // no end barrier: next hs/xbuf writes are fenced by this step's barriers
  }
}

// ---------------------------------------------------------------------------
extern "C" void kernel_launch(void* const* d_in, const int* in_sizes, int n_in,
                              void* d_out, int out_size, void* d_ws, size_t ws_size,
                              hipStream_t stream) {
  const int*   tokens = (const int*)d_in[0];
  const float* emb = (const float*)d_in[3];
  const float* Wxf = (const float*)d_in[4];
  const float* Whf = (const float*)d_in[5];
  const float* bxf = (const float*)d_in[6];
  const float* bhf = (const float*)d_in[7];
  const float* Wxb = (const float*)d_in[8];
  const float* Whb = (const float*)d_in[9];
  const float* bxb = (const float*)d_in[10];
  const float* bhb = (const float*)d_in[11];

  unsigned long long* h_ex = (unsigned long long*)d_ws;  // 32 KB

  hipFuncSetAttribute((const void*)bilstm_kernel,
                      hipFuncAttributeMaxDynamicSharedMemorySize, 65536);

  bilstm_kernel<<<dim3(256), dim3(256), 65536, stream>>>(
      tokens, emb, Wxf, Whf, bxf, bhf, Wxb, Whb, bxb, bhb,
      h_ex, (float*)d_out);
}